// Round 10
// baseline (1255.926 us; speedup 1.0000x reference)
//
#include <hip/hip_runtime.h>

#define LEAKY_SLOPE 0.01f
#define NUM_GRAPHS 512
#define TILE 2048            // edges per partition block
#define NB_MAX 1024          // max dst buckets (N <= 131072 at 128 nodes/bucket)
#define BKT_N 128            // nodes per bucket (dst >> 7)
#define POOL_SPAN 8          // graphs per block staged in LDS (overflow -> global)

typedef __attribute__((ext_vector_type(8))) short short8;   // 8 x bf16 (4 VGPRs)
typedef __attribute__((ext_vector_type(4))) float f32x4;    // MFMA C/D

static __device__ __forceinline__ unsigned short f2bf(float f) {
    unsigned u = __float_as_uint(f);
    u += 0x7FFFu + ((u >> 16) & 1u);
    return (unsigned short)(u >> 16);
}
static __device__ __forceinline__ float bf2f(unsigned short h) {
    return __uint_as_float(((unsigned)h) << 16);
}

static __device__ __forceinline__ int wave_incl_scan(int v, int lane) {
#pragma unroll
    for (int off = 1; off < 64; off <<= 1) {
        int t = __shfl_up(v, off, 64);
        if (lane >= off) v += t;
    }
    return v;
}

// ---------------------------------------------------------------------------
// mega_prep: range-split fused kernel (hist | x->bf16 | W->Bt pack)
// ---------------------------------------------------------------------------
__global__ __launch_bounds__(256)
void mega_prep(const int* __restrict__ dst, int* __restrict__ bucketCnt, int E,
               int NB, int histBlocks,
               const float* __restrict__ x, unsigned short* __restrict__ xB,
               int xElems /* N*16 float4s */, int xBlocks,
               const float* __restrict__ W1rel, const float* __restrict__ W1root,
               const float* __restrict__ W2rel, const float* __restrict__ W2root,
               unsigned short* __restrict__ Bt1, unsigned short* __restrict__ Bt2) {
    const int bid = blockIdx.x;
    if (bid < histBlocks) {
        __shared__ int h[NB_MAX];
        for (int t = threadIdx.x; t < NB_MAX; t += 256) h[t] = 0;
        __syncthreads();
        const int base = bid * TILE;
#pragma unroll
        for (int i = 0; i < TILE / 256; ++i) {
            int e = base + i * 256 + threadIdx.x;
            if (e < E) atomicAdd(&h[dst[e] >> 7], 1);
        }
        __syncthreads();
        for (int t = threadIdx.x; t < NB; t += 256)
            if (h[t]) atomicAdd(&bucketCnt[t], h[t]);
    } else if (bid < histBlocks + xBlocks) {
        int i = (bid - histBlocks) * 256 + threadIdx.x;
        if (i < xElems) {
            float4 f = ((const float4*)x)[i];
            ushort4 o = make_ushort4(f2bf(f.x), f2bf(f.y), f2bf(f.z), f2bf(f.w));
            ((ushort4*)xB)[i] = o;
        }
    } else {
        int b2 = bid - histBlocks - xBlocks;            // 0..7
        for (int idx = b2 * 2048 + threadIdx.x; idx < (b2 + 1) * 2048; idx += 256) {
            int which = idx >> 13;
            int j = idx & 8191;
            int n = j >> 7, k = j & 127;
            const float* Wr = which ? W2rel : W1rel;
            const float* Wo = which ? W2root : W1root;
            float v = (k < 64) ? Wr[k * 64 + n] : Wo[(k - 64) * 64 + n];
            (which ? Bt2 : Bt1)[j] = f2bf(v);
        }
    }
}

// ---------------------------------------------------------------------------
// bscan: exclusive scan of 1024 bucket counts -> bucketBase & cursors.
// ---------------------------------------------------------------------------
__global__ __launch_bounds__(1024)
void bscan_kernel(const int* __restrict__ bucketCnt, int* __restrict__ bucketBase,
                  int* __restrict__ cursor, int NB) {
    __shared__ int ws[16];
    const int t = threadIdx.x, lane = t & 63, wid = t >> 6;
    int v = (t < NB) ? bucketCnt[t] : 0;
    int s = wave_incl_scan(v, lane);
    if (lane == 63) ws[wid] = s;
    __syncthreads();
    int add = 0;
    for (int i = 0; i < wid; ++i) add += ws[i];
    if (t < NB) {
        int excl = s + add - v;
        bucketBase[t] = excl;
        cursor[t] = excl;
    }
}

// ---------------------------------------------------------------------------
// p1b: radix partition by dst>>7. Tile -> LDS hist/scan/reorder -> coalesced
// run writes. Payload: .x = src | (dst&127)<<20, .y = w bits.
// ---------------------------------------------------------------------------
__global__ __launch_bounds__(256)
void p1b_partition(const int* __restrict__ src, const int* __restrict__ dst,
                   const float* __restrict__ w, int* __restrict__ cursor,
                   int2* __restrict__ tmp, int E, int NB) {
    __shared__ int h[NB_MAX];
    __shared__ int cur[NB_MAX];
    __shared__ int lstart[NB_MAX];
    __shared__ int gbase[NB_MAX];
    __shared__ int ws[4];
    __shared__ int2 pay[TILE];
    __shared__ unsigned short bk[TILE];

    for (int t = threadIdx.x; t < NB_MAX; t += 256) h[t] = 0;
    __syncthreads();

    const int base = blockIdx.x * TILE;
    int   myb[TILE / 256];
    int   myp[TILE / 256];
    float myw[TILE / 256];
#pragma unroll
    for (int i = 0; i < TILE / 256; ++i) {
        int e = base + i * 256 + threadIdx.x;
        if (e < E) {
            int d = dst[e];
            myb[i] = d >> 7;
            myp[i] = src[e] | ((d & 127) << 20);
            myw[i] = w[e];
            atomicAdd(&h[myb[i]], 1);
        } else {
            myb[i] = -1;
        }
    }
    __syncthreads();

    {   // exclusive scan of h[0..1023] (thread t owns 4t..4t+3)
        const int t = threadIdx.x, lane = t & 63, wid = t >> 6;
        int a0 = h[4 * t], a1 = h[4 * t + 1], a2 = h[4 * t + 2], a3 = h[4 * t + 3];
        int tot = a0 + a1 + a2 + a3;
        int s = wave_incl_scan(tot, lane);
        if (lane == 63) ws[wid] = s;
        __syncthreads();
        int add = 0;
        for (int i = 0; i < wid; ++i) add += ws[i];
        int excl = s + add - tot;
        lstart[4 * t]     = excl;               cur[4 * t]     = excl;
        lstart[4 * t + 1] = excl + a0;          cur[4 * t + 1] = excl + a0;
        lstart[4 * t + 2] = excl + a0 + a1;     cur[4 * t + 2] = excl + a0 + a1;
        lstart[4 * t + 3] = excl + a0 + a1 + a2; cur[4 * t + 3] = excl + a0 + a1 + a2;
    }
    __syncthreads();

#pragma unroll
    for (int i = 0; i < TILE / 256; ++i) {
        if (myb[i] >= 0) {
            int p = atomicAdd(&cur[myb[i]], 1);
            pay[p] = make_int2(myp[i], __float_as_int(myw[i]));
            bk[p] = (unsigned short)myb[i];
        }
    }
    __syncthreads();

    for (int t = threadIdx.x; t < NB; t += 256) {
        int c = h[t];
        if (c) gbase[t] = atomicAdd(&cursor[t], c);
    }
    __syncthreads();

    const int total = min(TILE, E - base);
    for (int s2 = threadIdx.x; s2 < total; s2 += 256) {
        int b2 = bk[s2];
        tmp[gbase[b2] + s2 - lstart[b2]] = pay[s2];
    }
}

// ---------------------------------------------------------------------------
// bucket_gather: one block per 128-node bucket. Streams the bucket's edges
// exactly once (zero dead slots, perfect balance), accumulating into an LDS
// fp32 [128 x 65] tile (stride 65 breaks the 4-stride bank alias), then one
// coalesced bf16 write-out. Replaces rowStart CSR + node-per-wave gather and
// the p2 per-bucket sort entirely.
// ---------------------------------------------------------------------------
__global__ __launch_bounds__(256)
void bucket_gather(const unsigned short* __restrict__ xB, const int2* __restrict__ tmp,
                   const int* __restrict__ bucketBase, unsigned short* __restrict__ aggB,
                   int N, int E, int NB) {
    const int b = blockIdx.x;
    const int s = bucketBase[b];
    const int e = (b + 1 < NB) ? bucketBase[b + 1] : E;
    __shared__ float agg[BKT_N * 65];
    for (int i = threadIdx.x; i < BKT_N * 65; i += 256) agg[i] = 0.f;
    __syncthreads();

    const int grp = threadIdx.x >> 4;       // 0..15 edge slot across block
    const int f4  = (threadIdx.x & 15) * 4; // 4 features per lane
    const unsigned short* xf = xB + f4;

    for (int j0 = s; j0 < e; j0 += 32) {
        const int iA = j0 + grp;
        const int iB = j0 + 16 + grp;
        int2 eA = tmp[(iA < e) ? iA : s];       // clamped select-address (R7 lesson:
        int2 eB = tmp[(iB < e) ? iB : s];       //  never exec-mask the load chain)
        const float wA = (iA < e) ? __int_as_float(eA.y) : 0.0f;
        const float wB = (iB < e) ? __int_as_float(eB.y) : 0.0f;
        ushort4 rA = *(const ushort4*)(xf + (size_t)(eA.x & 0x1FFFF) * 64);
        ushort4 rB = *(const ushort4*)(xf + (size_t)(eB.x & 0x1FFFF) * 64);
        float* pA = &agg[((eA.x >> 20) & 127) * 65 + f4];
        float* pB = &agg[((eB.x >> 20) & 127) * 65 + f4];
        atomicAdd(pA + 0, bf2f(rA.x) * wA);
        atomicAdd(pA + 1, bf2f(rA.y) * wA);
        atomicAdd(pA + 2, bf2f(rA.z) * wA);
        atomicAdd(pA + 3, bf2f(rA.w) * wA);
        atomicAdd(pB + 0, bf2f(rB.x) * wB);
        atomicAdd(pB + 1, bf2f(rB.y) * wB);
        atomicAdd(pB + 2, bf2f(rB.z) * wB);
        atomicAdd(pB + 3, bf2f(rB.w) * wB);
    }
    __syncthreads();

    // write-out: 8192 feats, 4 per thread, ushort4 coalesced
#pragma unroll
    for (int base = 0; base < BKT_N * 64; base += 256 * 4) {
        int i = base + threadIdx.x * 4;
        int nl = i >> 6, f = i & 63;
        int node = b * BKT_N + nl;
        if (node < N) {
            ushort4 o = make_ushort4(f2bf(agg[nl * 65 + f]),
                                     f2bf(agg[nl * 65 + f + 1]),
                                     f2bf(agg[nl * 65 + f + 2]),
                                     f2bf(agg[nl * 65 + f + 3]));
            *(ushort4*)(aggB + (size_t)node * 64 + f) = o;
        }
    }
}

// ---------------------------------------------------------------------------
// Transform, store variant: swapped MFMA operands -> transposed D -> ushort4
// stores.
// ---------------------------------------------------------------------------
__global__ __launch_bounds__(256)
void transform_store(const unsigned short* __restrict__ aggB,
                     const unsigned short* __restrict__ rootB,
                     const unsigned short* __restrict__ Bt,
                     const float* __restrict__ bias,
                     unsigned short* __restrict__ xoutB, int N) {
    const int wave = threadIdx.x >> 6;
    const int lane = threadIdx.x & 63;
    const int quad = lane >> 4;
    const int l16  = lane & 15;
    const int m0   = blockIdx.x * 128 + wave * 32;

    short8 bf[4][4];
#pragma unroll
    for (int t = 0; t < 4; ++t)
#pragma unroll
        for (int k = 0; k < 4; ++k)
            bf[t][k] = *(const short8*)(Bt + (t * 16 + l16) * 128 + k * 32 + quad * 8);

    f32x4 acc[2][4];
#pragma unroll
    for (int s = 0; s < 2; ++s)
#pragma unroll
        for (int t = 0; t < 4; ++t)
            acc[s][t] = (f32x4){0.f, 0.f, 0.f, 0.f};

#pragma unroll
    for (int s = 0; s < 2; ++s) {
        int row = m0 + s * 16 + l16;
        int rowc = row < N ? row : N - 1;
        const unsigned short* arow = aggB  + (size_t)rowc * 64;
        const unsigned short* xrow = rootB + (size_t)rowc * 64;
        short8 af[4];
        af[0] = *(const short8*)(arow + quad * 8);
        af[1] = *(const short8*)(arow + 32 + quad * 8);
        af[2] = *(const short8*)(xrow + quad * 8);
        af[3] = *(const short8*)(xrow + 32 + quad * 8);
#pragma unroll
        for (int t = 0; t < 4; ++t)
#pragma unroll
            for (int k = 0; k < 4; ++k)
                acc[s][t] = __builtin_amdgcn_mfma_f32_16x16x32_bf16(bf[t][k], af[k],
                                                                    acc[s][t], 0, 0, 0);
    }

#pragma unroll
    for (int s = 0; s < 2; ++s) {
        const int node = m0 + s * 16 + l16;
        if (node < N) {
#pragma unroll
            for (int t = 0; t < 4; ++t) {
                const float4 bb = *(const float4*)(bias + t * 16 + quad * 4);
                float v0 = acc[s][t][0] + bb.x;
                float v1 = acc[s][t][1] + bb.y;
                float v2 = acc[s][t][2] + bb.z;
                float v3 = acc[s][t][3] + bb.w;
                v0 = (v0 > 0.f) ? v0 : LEAKY_SLOPE * v0;
                v1 = (v1 > 0.f) ? v1 : LEAKY_SLOPE * v1;
                v2 = (v2 > 0.f) ? v2 : LEAKY_SLOPE * v2;
                v3 = (v3 > 0.f) ? v3 : LEAKY_SLOPE * v3;
                ushort4 o = make_ushort4(f2bf(v0), f2bf(v1), f2bf(v2), f2bf(v3));
                *(ushort4*)(xoutB + (size_t)node * 64 + t * 16 + quad * 4) = o;
            }
        }
    }
}

// ---------------------------------------------------------------------------
// Transform, pool variant: LDS-staged pooling (kept from R9 — it gained
// ~20 us). Span overflow falls back to direct global atomics.
// ---------------------------------------------------------------------------
__global__ __launch_bounds__(256)
void transform_pool(const unsigned short* __restrict__ aggB,
                    const unsigned short* __restrict__ rootB,
                    const unsigned short* __restrict__ Bt,
                    const float* __restrict__ bias,
                    const int* __restrict__ batch,
                    float* __restrict__ pooled, int N) {
    const int wave = threadIdx.x >> 6;
    const int lane = threadIdx.x & 63;
    const int quad = lane >> 4;
    const int l16  = lane & 15;
    const int m0   = blockIdx.x * 128 + wave * 32;

    __shared__ float lpool[POOL_SPAN * 64];
    const int gmin = batch[blockIdx.x * 128];
    for (int i = threadIdx.x; i < POOL_SPAN * 64; i += 256) lpool[i] = 0.f;

    short8 bf[4][4];
#pragma unroll
    for (int t = 0; t < 4; ++t)
#pragma unroll
        for (int k = 0; k < 4; ++k)
            bf[t][k] = *(const short8*)(Bt + (t * 16 + l16) * 128 + k * 32 + quad * 8);

    f32x4 acc[2][4];
#pragma unroll
    for (int s = 0; s < 2; ++s)
#pragma unroll
        for (int t = 0; t < 4; ++t)
            acc[s][t] = (f32x4){0.f, 0.f, 0.f, 0.f};

#pragma unroll
    for (int s = 0; s < 2; ++s) {
        int row = m0 + s * 16 + l16;
        int rowc = row < N ? row : N - 1;
        const unsigned short* arow = aggB  + (size_t)rowc * 64;
        const unsigned short* xrow = rootB + (size_t)rowc * 64;
        short8 af[4];
        af[0] = *(const short8*)(arow + quad * 8);
        af[1] = *(const short8*)(arow + 32 + quad * 8);
        af[2] = *(const short8*)(xrow + quad * 8);
        af[3] = *(const short8*)(xrow + 32 + quad * 8);
#pragma unroll
        for (int t = 0; t < 4; ++t)
#pragma unroll
            for (int k = 0; k < 4; ++k)
                acc[s][t] = __builtin_amdgcn_mfma_f32_16x16x32_bf16(af[k], bf[t][k],
                                                                    acc[s][t], 0, 0, 0);
    }

    __syncthreads();   // lpool zero-init complete

#pragma unroll
    for (int s = 0; s < 2; ++s) {
#pragma unroll
        for (int t = 0; t < 4; ++t) {
            const int col = t * 16 + l16;
            const float b = bias[col];
            const int rowbase = m0 + s * 16 + quad * 4;
            float v[4]; int g[4]; int nv = 0;
#pragma unroll
            for (int r = 0; r < 4; ++r) {
                int row = rowbase + r;
                if (row < N) {
                    float a = acc[s][t][r] + b;
                    a = (a > 0.0f) ? a : LEAKY_SLOPE * a;
                    v[nv] = a;
                    g[nv] = batch[row];
                    ++nv;
                }
            }
            if (nv == 4 && g[0] == g[3]) {
                int gl = g[0] - gmin;
                float sum = v[0] + v[1] + v[2] + v[3];
                if (gl < POOL_SPAN) atomicAdd(&lpool[gl * 64 + col], sum);
                else                atomicAdd(&pooled[g[0] * 64 + col], sum);
            } else {
                for (int r = 0; r < nv; ++r) {
                    int gl = g[r] - gmin;
                    if (gl < POOL_SPAN) atomicAdd(&lpool[gl * 64 + col], v[r]);
                    else                atomicAdd(&pooled[g[r] * 64 + col], v[r]);
                }
            }
        }
    }

    __syncthreads();
    for (int i = threadIdx.x; i < POOL_SPAN * 64; i += 256) {
        float v = lpool[i];
        if (v != 0.0f)
            atomicAdd(&pooled[(gmin + (i >> 6)) * 64 + (i & 63)], v);
    }
}

// ---------------------------------------------------------------------------
// Final: cnt via binary search on sorted batch; tiny GEMM epilogue.
// ---------------------------------------------------------------------------
__global__ __launch_bounds__(64)
void final_kernel(const float* __restrict__ pooled, const int* __restrict__ batch,
                  int N, const float* __restrict__ Wl, const float* __restrict__ bl,
                  float* __restrict__ out) {
    const int g = blockIdx.x;
    const int j = threadIdx.x;
    __shared__ float sp[64];
    __shared__ int scnt;
    if (j == 0) {
        int lo = 0, hi = N;
        while (lo < hi) { int mid = (lo + hi) >> 1; if (batch[mid] < g) lo = mid + 1; else hi = mid; }
        const int start = lo;
        hi = N;
        while (lo < hi) { int mid = (lo + hi) >> 1; if (batch[mid] < g + 1) lo = mid + 1; else hi = mid; }
        scnt = lo - start;
    }
    __syncthreads();
    const float c = fmaxf((float)scnt, 1.0f);
    sp[j] = pooled[g * 64 + j] / c;
    __syncthreads();
    if (j < 8) {
        float acc = bl[j];
#pragma unroll
        for (int k = 0; k < 64; ++k) acc += sp[k] * Wl[k * 8 + j];
        out[g * 8 + j] = acc;
    }
}

extern "C" void kernel_launch(void* const* d_in, const int* in_sizes, int n_in,
                              void* d_out, int out_size, void* d_ws, size_t ws_size,
                              hipStream_t stream) {
    const float* x      = (const float*)d_in[0];
    const int*   ei     = (const int*)  d_in[1];  // [2,E]: src then dst
    const float* w      = (const float*)d_in[2];
    const int*   batch  = (const int*)  d_in[3];
    const float* W1root = (const float*)d_in[4];
    const float* W1rel  = (const float*)d_in[5];
    const float* b1     = (const float*)d_in[6];
    const float* W2root = (const float*)d_in[7];
    const float* W2rel  = (const float*)d_in[8];
    const float* b2     = (const float*)d_in[9];
    const float* Wl     = (const float*)d_in[10];
    const float* bl     = (const float*)d_in[11];
    float* out = (float*)d_out;

    const int E = in_sizes[2];      // 1,250,000
    const int N = in_sizes[3];      // 100,000
    const int* src = ei;
    const int* dst = ei + E;
    const int NB = (N + BKT_N - 1) / BKT_N;   // 782 buckets of 128 nodes

    // Workspace layout
    unsigned short* xB   = (unsigned short*)d_ws;          // [N*64] bf16
    unsigned short* aggB = xB   + (size_t)N * 64;          // [N*64]
    unsigned short* x1B  = aggB + (size_t)N * 64;          // [N*64]
    int2*  tmp      = (int2*)(x1B + (size_t)N * 64);       // [E] bucket-partitioned
    unsigned short* Bt1 = (unsigned short*)(tmp + E);      // [64*128]
    unsigned short* Bt2 = Bt1 + 64 * 128;                  // [64*128]
    int*   bucketCnt  = (int*)(Bt2 + 64 * 128);            // [1024]
    int*   bucketBase = bucketCnt + NB_MAX;                // [1024]
    int*   cursor     = bucketBase + NB_MAX;               // [1024]
    float* pooled   = (float*)(cursor + NB_MAX);           // [512*64]

    const int histBlocks = (E + TILE - 1) / TILE;          // 611
    const int xElems = N * 16;                              // float4 count
    const int xBlocks = (xElems + 255) / 256;               // 6250

    // ---- build + prep ----
    hipMemsetAsync(bucketCnt, 0, (3 * NB_MAX + NUM_GRAPHS * 64) * sizeof(float), stream);
    mega_prep<<<histBlocks + xBlocks + 8, 256, 0, stream>>>(
        dst, bucketCnt, E, NB, histBlocks,
        x, xB, xElems, xBlocks,
        W1rel, W1root, W2rel, W2root, Bt1, Bt2);
    bscan_kernel<<<1, 1024, 0, stream>>>(bucketCnt, bucketBase, cursor, NB);
    p1b_partition<<<histBlocks, 256, 0, stream>>>(src, dst, w, cursor, tmp, E, NB);

    const int tBlocks = (N + 127) / 128;
    // ---- Layer 1 ----
    bucket_gather<<<NB, 256, 0, stream>>>(xB, tmp, bucketBase, aggB, N, E, NB);
    transform_store<<<tBlocks, 256, 0, stream>>>(aggB, xB, Bt1, b1, x1B, N);
    // ---- Layer 2 ----
    bucket_gather<<<NB, 256, 0, stream>>>(x1B, tmp, bucketBase, aggB, N, E, NB);
    transform_pool<<<tBlocks, 256, 0, stream>>>(aggB, x1B, Bt2, b2, batch, pooled, N);
    // ---- Pool + classify ----
    final_kernel<<<NUM_GRAPHS, 64, 0, stream>>>(pooled, batch, N, Wl, bl, out);
}

// Round 11
// 283.288 us; speedup vs baseline: 4.4334x; 4.4334x over previous
//
#include <hip/hip_runtime.h>

#define LEAKY_SLOPE 0.01f
#define NUM_GRAPHS 512
#define TILE 2048            // edges per partition block
#define NB_MAX 512           // max dst buckets (N <= 131072)
#define POOL_SPAN 8          // graphs per block staged in LDS (overflow -> global)

typedef __attribute__((ext_vector_type(8))) short short8;   // 8 x bf16 (4 VGPRs)
typedef __attribute__((ext_vector_type(4))) float f32x4;    // MFMA C/D

static __device__ __forceinline__ unsigned short f2bf(float f) {
    unsigned u = __float_as_uint(f);
    u += 0x7FFFu + ((u >> 16) & 1u);
    return (unsigned short)(u >> 16);
}
static __device__ __forceinline__ float bf2f(unsigned short h) {
    return __uint_as_float(((unsigned)h) << 16);
}

static __device__ __forceinline__ int wave_incl_scan(int v, int lane) {
#pragma unroll
    for (int off = 1; off < 64; off <<= 1) {
        int t = __shfl_up(v, off, 64);
        if (lane >= off) v += t;
    }
    return v;
}

// ---------------------------------------------------------------------------
// mega_prep: range-split fused kernel (hist | x->bf16 | W->Bt pack)
// ---------------------------------------------------------------------------
__global__ __launch_bounds__(256)
void mega_prep(const int* __restrict__ dst, int* __restrict__ bucketCnt, int E,
               int NB, int histBlocks,
               const float* __restrict__ x, unsigned short* __restrict__ xB,
               int xElems /* N*16 float4s */, int xBlocks,
               const float* __restrict__ W1rel, const float* __restrict__ W1root,
               const float* __restrict__ W2rel, const float* __restrict__ W2root,
               unsigned short* __restrict__ Bt1, unsigned short* __restrict__ Bt2) {
    const int bid = blockIdx.x;
    if (bid < histBlocks) {
        __shared__ int h[NB_MAX];
        for (int t = threadIdx.x; t < NB_MAX; t += 256) h[t] = 0;
        __syncthreads();
        const int base = bid * TILE;
#pragma unroll
        for (int i = 0; i < TILE / 256; ++i) {
            int e = base + i * 256 + threadIdx.x;
            if (e < E) atomicAdd(&h[dst[e] >> 8], 1);
        }
        __syncthreads();
        for (int t = threadIdx.x; t < NB; t += 256)
            if (h[t]) atomicAdd(&bucketCnt[t], h[t]);
    } else if (bid < histBlocks + xBlocks) {
        int i = (bid - histBlocks) * 256 + threadIdx.x;
        if (i < xElems) {
            float4 f = ((const float4*)x)[i];
            ushort4 o = make_ushort4(f2bf(f.x), f2bf(f.y), f2bf(f.z), f2bf(f.w));
            ((ushort4*)xB)[i] = o;
        }
    } else {
        int b2 = bid - histBlocks - xBlocks;            // 0..7
        for (int idx = b2 * 2048 + threadIdx.x; idx < (b2 + 1) * 2048; idx += 256) {
            int which = idx >> 13;
            int j = idx & 8191;
            int n = j >> 7, k = j & 127;
            const float* Wr = which ? W2rel : W1rel;
            const float* Wo = which ? W2root : W1root;
            float v = (k < 64) ? Wr[k * 64 + n] : Wo[(k - 64) * 64 + n];
            (which ? Bt2 : Bt1)[j] = f2bf(v);
        }
    }
}

// ---------------------------------------------------------------------------
// bscan: exclusive scan of bucket counts -> bucketBase & cursors; rowStart[N]=E
// ---------------------------------------------------------------------------
__global__ __launch_bounds__(512)
void bscan_kernel(const int* __restrict__ bucketCnt, int* __restrict__ bucketBase,
                  int* __restrict__ cursor, int* __restrict__ rowStart,
                  int N, int E, int NB) {
    __shared__ int ws[8];
    const int t = threadIdx.x, lane = t & 63, wid = t >> 6;
    int v = (t < NB) ? bucketCnt[t] : 0;
    int s = wave_incl_scan(v, lane);
    if (lane == 63) ws[wid] = s;
    __syncthreads();
    int add = 0;
    for (int i = 0; i < wid; ++i) add += ws[i];
    if (t < NB) {
        int excl = s + add - v;
        bucketBase[t] = excl;
        cursor[t] = excl;
    }
    if (t == 0) rowStart[N] = E;
}

// ---------------------------------------------------------------------------
// p1b: radix partition by dst>>8. Tile -> LDS hist/scan/reorder -> coalesced
// run writes. Payload: .x = src | (dst&255)<<20, .y = w bits.
// ---------------------------------------------------------------------------
__global__ __launch_bounds__(256)
void p1b_partition(const int* __restrict__ src, const int* __restrict__ dst,
                   const float* __restrict__ w, int* __restrict__ cursor,
                   int2* __restrict__ tmp, int E, int NB) {
    __shared__ int h[NB_MAX];
    __shared__ int cur[NB_MAX];
    __shared__ int lstart[NB_MAX];
    __shared__ int gbase[NB_MAX];
    __shared__ int ws[4];
    __shared__ int2 pay[TILE];
    __shared__ unsigned short bk[TILE];

    for (int t = threadIdx.x; t < NB_MAX; t += 256) h[t] = 0;
    __syncthreads();

    const int base = blockIdx.x * TILE;
    int   myb[TILE / 256];
    int   myp[TILE / 256];
    float myw[TILE / 256];
#pragma unroll
    for (int i = 0; i < TILE / 256; ++i) {
        int e = base + i * 256 + threadIdx.x;
        if (e < E) {
            int d = dst[e];
            myb[i] = d >> 8;
            myp[i] = src[e] | ((d & 255) << 20);
            myw[i] = w[e];
            atomicAdd(&h[myb[i]], 1);
        } else {
            myb[i] = -1;
        }
    }
    __syncthreads();

    {   // exclusive scan of h[0..511] (thread t owns 2t, 2t+1)
        const int t = threadIdx.x, lane = t & 63, wid = t >> 6;
        int a = h[2 * t], b = h[2 * t + 1];
        int s = wave_incl_scan(a + b, lane);
        if (lane == 63) ws[wid] = s;
        __syncthreads();
        int add = 0;
        for (int i = 0; i < wid; ++i) add += ws[i];
        int excl = s + add - (a + b);
        lstart[2 * t] = excl;
        lstart[2 * t + 1] = excl + a;
        cur[2 * t] = excl;
        cur[2 * t + 1] = excl + a;
    }
    __syncthreads();

#pragma unroll
    for (int i = 0; i < TILE / 256; ++i) {
        if (myb[i] >= 0) {
            int p = atomicAdd(&cur[myb[i]], 1);
            pay[p] = make_int2(myp[i], __float_as_int(myw[i]));
            bk[p] = (unsigned short)myb[i];
        }
    }
    __syncthreads();

    for (int t = threadIdx.x; t < NB; t += 256) {
        int c = h[t];
        if (c) gbase[t] = atomicAdd(&cursor[t], c);
    }
    __syncthreads();

    const int total = min(TILE, E - base);
    for (int s2 = threadIdx.x; s2 < total; s2 += 256) {
        int b2 = bk[s2];
        tmp[gbase[b2] + s2 - lstart[b2]] = pay[s2];
    }
}

// ---------------------------------------------------------------------------
// p2: one block per bucket. LDS hist of 256 local dst -> scan -> rowStart +
// final dst-sorted edata (src, w fp32).
// ---------------------------------------------------------------------------
__global__ __launch_bounds__(256)
void p2_build(const int2* __restrict__ tmp, const int* __restrict__ bucketBase,
              int* __restrict__ rowStart, int2* __restrict__ edata,
              int N, int E, int NB) {
    const int b = blockIdx.x;
    const int s = bucketBase[b];
    const int e2 = (b + 1 < NB) ? bucketBase[b + 1] : E;
    __shared__ int h[256];
    __shared__ int cur[256];
    __shared__ int ws[4];
    h[threadIdx.x] = 0;
    __syncthreads();
    for (int j = s + threadIdx.x; j < e2; j += 256) {
        int dl = (tmp[j].x >> 20) & 255;
        atomicAdd(&h[dl], 1);
    }
    __syncthreads();
    const int t = threadIdx.x, lane = t & 63, wid = t >> 6;
    int v = h[t];
    int sc = wave_incl_scan(v, lane);
    if (lane == 63) ws[wid] = sc;
    __syncthreads();
    int add = 0;
    for (int i = 0; i < wid; ++i) add += ws[i];
    int excl = sc + add - v;
    const int node = b * 256 + t;
    if (node < N) rowStart[node] = s + excl;
    cur[t] = excl;
    __syncthreads();
    for (int j = s + threadIdx.x; j < e2; j += 256) {
        int2 v2 = tmp[j];
        int dl = (v2.x >> 20) & 255;
        int p = atomicAdd(&cur[dl], 1);
        edata[s + p] = make_int2(v2.x & 0x1FFFF, v2.y);
    }
}

// ---------------------------------------------------------------------------
// Gather, 16-edge-parallel, unconditional clamped loads (R8's proven shape:
// select on address, zero on weight; 4 edata + 4 row loads in flight).
// ---------------------------------------------------------------------------
__global__ __launch_bounds__(256)
void gather_kernel(const unsigned short* __restrict__ xB, const int* __restrict__ rowStart,
                   const int2* __restrict__ edata, unsigned short* __restrict__ aggB, int N) {
    const int node = blockIdx.x * 4 + (threadIdx.x >> 6);
    if (node >= N) return;
    const int lane = threadIdx.x & 63;
    const int grp  = lane >> 4;          // edge slot within quad
    const int f4   = (lane & 15) * 4;    // feature base (4 features/lane)
    const int s = rowStart[node];
    const int e = rowStart[node + 1];

    float a0 = 0.f, a1 = 0.f, a2 = 0.f, a3 = 0.f;
    for (int j = s; j < e; j += 16) {
        int   idx[4];
        int2  ed[4];
#pragma unroll
        for (int u = 0; u < 4; ++u) {
            int ii = j + u * 4 + grp;
            idx[u] = (ii < e) ? ii : s;
            ed[u] = edata[idx[u]];
        }
        ushort4 r[4];
#pragma unroll
        for (int u = 0; u < 4; ++u)
            r[u] = *(const ushort4*)(xB + (size_t)ed[u].x * 64 + f4);
#pragma unroll
        for (int u = 0; u < 4; ++u) {
            int ii = j + u * 4 + grp;
            float wv = (ii < e) ? __int_as_float(ed[u].y) : 0.0f;
            a0 += bf2f(r[u].x) * wv;  a1 += bf2f(r[u].y) * wv;
            a2 += bf2f(r[u].z) * wv;  a3 += bf2f(r[u].w) * wv;
        }
    }
    a0 += __shfl_xor(a0, 16, 64);  a1 += __shfl_xor(a1, 16, 64);
    a2 += __shfl_xor(a2, 16, 64);  a3 += __shfl_xor(a3, 16, 64);
    a0 += __shfl_xor(a0, 32, 64);  a1 += __shfl_xor(a1, 32, 64);
    a2 += __shfl_xor(a2, 32, 64);  a3 += __shfl_xor(a3, 32, 64);
    if (grp == 0) {
        ushort4 o = make_ushort4(f2bf(a0), f2bf(a1), f2bf(a2), f2bf(a3));
        *(ushort4*)(aggB + (size_t)node * 64 + f4) = o;
    }
}

// ---------------------------------------------------------------------------
// Transform, store variant: swapped MFMA operands -> transposed D -> ushort4
// stores.
// ---------------------------------------------------------------------------
__global__ __launch_bounds__(256)
void transform_store(const unsigned short* __restrict__ aggB,
                     const unsigned short* __restrict__ rootB,
                     const unsigned short* __restrict__ Bt,
                     const float* __restrict__ bias,
                     unsigned short* __restrict__ xoutB, int N) {
    const int wave = threadIdx.x >> 6;
    const int lane = threadIdx.x & 63;
    const int quad = lane >> 4;
    const int l16  = lane & 15;
    const int m0   = blockIdx.x * 128 + wave * 32;

    short8 bf[4][4];
#pragma unroll
    for (int t = 0; t < 4; ++t)
#pragma unroll
        for (int k = 0; k < 4; ++k)
            bf[t][k] = *(const short8*)(Bt + (t * 16 + l16) * 128 + k * 32 + quad * 8);

    f32x4 acc[2][4];
#pragma unroll
    for (int s = 0; s < 2; ++s)
#pragma unroll
        for (int t = 0; t < 4; ++t)
            acc[s][t] = (f32x4){0.f, 0.f, 0.f, 0.f};

#pragma unroll
    for (int s = 0; s < 2; ++s) {
        int row = m0 + s * 16 + l16;
        int rowc = row < N ? row : N - 1;
        const unsigned short* arow = aggB  + (size_t)rowc * 64;
        const unsigned short* xrow = rootB + (size_t)rowc * 64;
        short8 af[4];
        af[0] = *(const short8*)(arow + quad * 8);
        af[1] = *(const short8*)(arow + 32 + quad * 8);
        af[2] = *(const short8*)(xrow + quad * 8);
        af[3] = *(const short8*)(xrow + 32 + quad * 8);
#pragma unroll
        for (int t = 0; t < 4; ++t)
#pragma unroll
            for (int k = 0; k < 4; ++k)
                acc[s][t] = __builtin_amdgcn_mfma_f32_16x16x32_bf16(bf[t][k], af[k],
                                                                    acc[s][t], 0, 0, 0);
    }

#pragma unroll
    for (int s = 0; s < 2; ++s) {
        const int node = m0 + s * 16 + l16;
        if (node < N) {
#pragma unroll
            for (int t = 0; t < 4; ++t) {
                const float4 bb = *(const float4*)(bias + t * 16 + quad * 4);
                float v0 = acc[s][t][0] + bb.x;
                float v1 = acc[s][t][1] + bb.y;
                float v2 = acc[s][t][2] + bb.z;
                float v3 = acc[s][t][3] + bb.w;
                v0 = (v0 > 0.f) ? v0 : LEAKY_SLOPE * v0;
                v1 = (v1 > 0.f) ? v1 : LEAKY_SLOPE * v1;
                v2 = (v2 > 0.f) ? v2 : LEAKY_SLOPE * v2;
                v3 = (v3 > 0.f) ? v3 : LEAKY_SLOPE * v3;
                ushort4 o = make_ushort4(f2bf(v0), f2bf(v1), f2bf(v2), f2bf(v3));
                *(ushort4*)(xoutB + (size_t)node * 64 + t * 16 + quad * 4) = o;
            }
        }
    }
}

// ---------------------------------------------------------------------------
// Transform, pool variant: LDS-staged pooling (R9's win, ~20 us). batch is
// sorted; a 128-node block spans <=2 graphs in practice. Span overflow falls
// back to direct global atomics (correctness never depends on distribution).
// ---------------------------------------------------------------------------
__global__ __launch_bounds__(256)
void transform_pool(const unsigned short* __restrict__ aggB,
                    const unsigned short* __restrict__ rootB,
                    const unsigned short* __restrict__ Bt,
                    const float* __restrict__ bias,
                    const int* __restrict__ batch,
                    float* __restrict__ pooled, int N) {
    const int wave = threadIdx.x >> 6;
    const int lane = threadIdx.x & 63;
    const int quad = lane >> 4;
    const int l16  = lane & 15;
    const int m0   = blockIdx.x * 128 + wave * 32;

    __shared__ float lpool[POOL_SPAN * 64];
    const int gmin = batch[blockIdx.x * 128];
    for (int i = threadIdx.x; i < POOL_SPAN * 64; i += 256) lpool[i] = 0.f;

    short8 bf[4][4];
#pragma unroll
    for (int t = 0; t < 4; ++t)
#pragma unroll
        for (int k = 0; k < 4; ++k)
            bf[t][k] = *(const short8*)(Bt + (t * 16 + l16) * 128 + k * 32 + quad * 8);

    f32x4 acc[2][4];
#pragma unroll
    for (int s = 0; s < 2; ++s)
#pragma unroll
        for (int t = 0; t < 4; ++t)
            acc[s][t] = (f32x4){0.f, 0.f, 0.f, 0.f};

#pragma unroll
    for (int s = 0; s < 2; ++s) {
        int row = m0 + s * 16 + l16;
        int rowc = row < N ? row : N - 1;
        const unsigned short* arow = aggB  + (size_t)rowc * 64;
        const unsigned short* xrow = rootB + (size_t)rowc * 64;
        short8 af[4];
        af[0] = *(const short8*)(arow + quad * 8);
        af[1] = *(const short8*)(arow + 32 + quad * 8);
        af[2] = *(const short8*)(xrow + quad * 8);
        af[3] = *(const short8*)(xrow + 32 + quad * 8);
#pragma unroll
        for (int t = 0; t < 4; ++t)
#pragma unroll
            for (int k = 0; k < 4; ++k)
                acc[s][t] = __builtin_amdgcn_mfma_f32_16x16x32_bf16(af[k], bf[t][k],
                                                                    acc[s][t], 0, 0, 0);
    }

    __syncthreads();   // lpool zero-init complete

#pragma unroll
    for (int s = 0; s < 2; ++s) {
#pragma unroll
        for (int t = 0; t < 4; ++t) {
            const int col = t * 16 + l16;
            const float b = bias[col];
            const int rowbase = m0 + s * 16 + quad * 4;
            float v[4]; int g[4]; int nv = 0;
#pragma unroll
            for (int r = 0; r < 4; ++r) {
                int row = rowbase + r;
                if (row < N) {
                    float a = acc[s][t][r] + b;
                    a = (a > 0.0f) ? a : LEAKY_SLOPE * a;
                    v[nv] = a;
                    g[nv] = batch[row];
                    ++nv;
                }
            }
            if (nv == 4 && g[0] == g[3]) {
                int gl = g[0] - gmin;
                float sum = v[0] + v[1] + v[2] + v[3];
                if (gl < POOL_SPAN) atomicAdd(&lpool[gl * 64 + col], sum);
                else                atomicAdd(&pooled[g[0] * 64 + col], sum);
            } else {
                for (int r = 0; r < nv; ++r) {
                    int gl = g[r] - gmin;
                    if (gl < POOL_SPAN) atomicAdd(&lpool[gl * 64 + col], v[r]);
                    else                atomicAdd(&pooled[g[r] * 64 + col], v[r]);
                }
            }
        }
    }

    __syncthreads();
    for (int i = threadIdx.x; i < POOL_SPAN * 64; i += 256) {
        float v = lpool[i];
        if (v != 0.0f)
            atomicAdd(&pooled[(gmin + (i >> 6)) * 64 + (i & 63)], v);
    }
}

// ---------------------------------------------------------------------------
// Final: cnt via binary search on sorted batch; tiny GEMM epilogue.
// ---------------------------------------------------------------------------
__global__ __launch_bounds__(64)
void final_kernel(const float* __restrict__ pooled, const int* __restrict__ batch,
                  int N, const float* __restrict__ Wl, const float* __restrict__ bl,
                  float* __restrict__ out) {
    const int g = blockIdx.x;
    const int j = threadIdx.x;
    __shared__ float sp[64];
    __shared__ int scnt;
    if (j == 0) {
        int lo = 0, hi = N;
        while (lo < hi) { int mid = (lo + hi) >> 1; if (batch[mid] < g) lo = mid + 1; else hi = mid; }
        const int start = lo;
        hi = N;
        while (lo < hi) { int mid = (lo + hi) >> 1; if (batch[mid] < g + 1) lo = mid + 1; else hi = mid; }
        scnt = lo - start;
    }
    __syncthreads();
    const float c = fmaxf((float)scnt, 1.0f);
    sp[j] = pooled[g * 64 + j] / c;
    __syncthreads();
    if (j < 8) {
        float acc = bl[j];
#pragma unroll
        for (int k = 0; k < 64; ++k) acc += sp[k] * Wl[k * 8 + j];
        out[g * 8 + j] = acc;
    }
}

extern "C" void kernel_launch(void* const* d_in, const int* in_sizes, int n_in,
                              void* d_out, int out_size, void* d_ws, size_t ws_size,
                              hipStream_t stream) {
    const float* x      = (const float*)d_in[0];
    const int*   ei     = (const int*)  d_in[1];  // [2,E]: src then dst
    const float* w      = (const float*)d_in[2];
    const int*   batch  = (const int*)  d_in[3];
    const float* W1root = (const float*)d_in[4];
    const float* W1rel  = (const float*)d_in[5];
    const float* b1     = (const float*)d_in[6];
    const float* W2root = (const float*)d_in[7];
    const float* W2rel  = (const float*)d_in[8];
    const float* b2     = (const float*)d_in[9];
    const float* Wl     = (const float*)d_in[10];
    const float* bl     = (const float*)d_in[11];
    float* out = (float*)d_out;

    const int E = in_sizes[2];      // 1,250,000
    const int N = in_sizes[3];      // 100,000
    const int* src = ei;
    const int* dst = ei + E;
    const int NB = (N + 255) / 256; // 391 dst buckets

    // Workspace layout
    unsigned short* xB   = (unsigned short*)d_ws;          // [N*64] bf16
    unsigned short* aggB = xB   + (size_t)N * 64;          // [N*64]
    unsigned short* x1B  = aggB + (size_t)N * 64;          // [N*64]
    int2*  tmp      = (int2*)(x1B + (size_t)N * 64);       // [E]
    int2*  edata    = tmp + E;                             // [E]
    unsigned short* Bt1 = (unsigned short*)(edata + E);    // [64*128]
    unsigned short* Bt2 = Bt1 + 64 * 128;                  // [64*128]
    int*   rowStart = (int*)(Bt2 + 64 * 128);              // [N+1]
    int*   bucketCnt  = rowStart + (N + 1);                // [512]
    int*   bucketBase = bucketCnt + NB_MAX;                // [512]
    int*   cursor     = bucketBase + NB_MAX;               // [512]
    float* pooled   = (float*)(cursor + NB_MAX);           // [512*64]

    const int histBlocks = (E + TILE - 1) / TILE;          // 611
    const int xElems = N * 16;                              // float4 count
    const int xBlocks = (xElems + 255) / 256;               // 6250

    // ---- build + prep ----
    hipMemsetAsync(bucketCnt, 0, (3 * NB_MAX + NUM_GRAPHS * 64) * sizeof(float), stream);
    mega_prep<<<histBlocks + xBlocks + 8, 256, 0, stream>>>(
        dst, bucketCnt, E, NB, histBlocks,
        x, xB, xElems, xBlocks,
        W1rel, W1root, W2rel, W2root, Bt1, Bt2);
    bscan_kernel<<<1, 512, 0, stream>>>(bucketCnt, bucketBase, cursor, rowStart, N, E, NB);
    p1b_partition<<<histBlocks, 256, 0, stream>>>(src, dst, w, cursor, tmp, E, NB);
    p2_build<<<NB, 256, 0, stream>>>(tmp, bucketBase, rowStart, edata, N, E, NB);

    const int tBlocks = (N + 127) / 128;
    // ---- Layer 1 ----
    gather_kernel<<<(N + 3) / 4, 256, 0, stream>>>(xB, rowStart, edata, aggB, N);
    transform_store<<<tBlocks, 256, 0, stream>>>(aggB, xB, Bt1, b1, x1B, N);
    // ---- Layer 2 ----
    gather_kernel<<<(N + 3) / 4, 256, 0, stream>>>(x1B, rowStart, edata, aggB, N);
    transform_pool<<<tBlocks, 256, 0, stream>>>(aggB, x1B, Bt2, b2, batch, pooled, N);
    // ---- Pool + classify ----
    final_kernel<<<NUM_GRAPHS, 64, 0, stream>>>(pooled, batch, N, Wl, bl, out);
}

// Round 12
// 272.453 us; speedup vs baseline: 4.6097x; 1.0398x over previous
//
#include <hip/hip_runtime.h>

#define LEAKY_SLOPE 0.01f
#define NUM_GRAPHS 512
#define TILE 4096            // edges per partition block (4096: 10.5-edge write runs,
                             //  ~2x lower scattered-write amplification than 2048)
#define NB_MAX 512           // max dst buckets (N <= 131072)
#define POOL_SPAN 8          // graphs per block staged in LDS (overflow -> global)

typedef __attribute__((ext_vector_type(8))) short short8;   // 8 x bf16 (4 VGPRs)
typedef __attribute__((ext_vector_type(4))) float f32x4;    // MFMA C/D

static __device__ __forceinline__ unsigned short f2bf(float f) {
    unsigned u = __float_as_uint(f);
    u += 0x7FFFu + ((u >> 16) & 1u);
    return (unsigned short)(u >> 16);
}
static __device__ __forceinline__ float bf2f(unsigned short h) {
    return __uint_as_float(((unsigned)h) << 16);
}

static __device__ __forceinline__ int wave_incl_scan(int v, int lane) {
#pragma unroll
    for (int off = 1; off < 64; off <<= 1) {
        int t = __shfl_up(v, off, 64);
        if (lane >= off) v += t;
    }
    return v;
}

// ---------------------------------------------------------------------------
// mega_prep: range-split fused kernel (hist | x->bf16 | W->Bt pack)
// ---------------------------------------------------------------------------
__global__ __launch_bounds__(256)
void mega_prep(const int* __restrict__ dst, int* __restrict__ bucketCnt, int E,
               int NB, int histBlocks,
               const float* __restrict__ x, unsigned short* __restrict__ xB,
               int xElems /* N*16 float4s */, int xBlocks,
               const float* __restrict__ W1rel, const float* __restrict__ W1root,
               const float* __restrict__ W2rel, const float* __restrict__ W2root,
               unsigned short* __restrict__ Bt1, unsigned short* __restrict__ Bt2) {
    const int bid = blockIdx.x;
    if (bid < histBlocks) {
        __shared__ int h[NB_MAX];
        for (int t = threadIdx.x; t < NB_MAX; t += 256) h[t] = 0;
        __syncthreads();
        const int base = bid * TILE;
#pragma unroll
        for (int i = 0; i < TILE / 256; ++i) {
            int e = base + i * 256 + threadIdx.x;
            if (e < E) atomicAdd(&h[dst[e] >> 8], 1);
        }
        __syncthreads();
        for (int t = threadIdx.x; t < NB; t += 256)
            if (h[t]) atomicAdd(&bucketCnt[t], h[t]);
    } else if (bid < histBlocks + xBlocks) {
        int i = (bid - histBlocks) * 256 + threadIdx.x;
        if (i < xElems) {
            float4 f = ((const float4*)x)[i];
            ushort4 o = make_ushort4(f2bf(f.x), f2bf(f.y), f2bf(f.z), f2bf(f.w));
            ((ushort4*)xB)[i] = o;
        }
    } else {
        int b2 = bid - histBlocks - xBlocks;            // 0..7
        for (int idx = b2 * 2048 + threadIdx.x; idx < (b2 + 1) * 2048; idx += 256) {
            int which = idx >> 13;
            int j = idx & 8191;
            int n = j >> 7, k = j & 127;
            const float* Wr = which ? W2rel : W1rel;
            const float* Wo = which ? W2root : W1root;
            float v = (k < 64) ? Wr[k * 64 + n] : Wo[(k - 64) * 64 + n];
            (which ? Bt2 : Bt1)[j] = f2bf(v);
        }
    }
}

// ---------------------------------------------------------------------------
// bscan: exclusive scan of bucket counts -> bucketBase & cursors; rowStart[N]=E;
// also zeroes pooled (folds the big memset away).
// ---------------------------------------------------------------------------
__global__ __launch_bounds__(512)
void bscan_kernel(const int* __restrict__ bucketCnt, int* __restrict__ bucketBase,
                  int* __restrict__ cursor, int* __restrict__ rowStart,
                  float* __restrict__ pooled, int N, int E, int NB) {
    __shared__ int ws[8];
    const int t = threadIdx.x, lane = t & 63, wid = t >> 6;
    int v = (t < NB) ? bucketCnt[t] : 0;
    int s = wave_incl_scan(v, lane);
    if (lane == 63) ws[wid] = s;
    __syncthreads();
    int add = 0;
    for (int i = 0; i < wid; ++i) add += ws[i];
    if (t < NB) {
        int excl = s + add - v;
        bucketBase[t] = excl;
        cursor[t] = excl;
    }
    if (t == 0) rowStart[N] = E;
    // zero pooled: 512 threads x 64 floats (float4-wide)
    float4 z = make_float4(0.f, 0.f, 0.f, 0.f);
#pragma unroll
    for (int i = 0; i < 16; ++i)
        ((float4*)pooled)[t * 16 + i] = z;
}

// ---------------------------------------------------------------------------
// p1b: radix partition by dst>>8. Tile -> LDS hist/scan/reorder -> coalesced
// run writes. Payload: .x = src | (dst&255)<<20, .y = w bits.
// ---------------------------------------------------------------------------
__global__ __launch_bounds__(256)
void p1b_partition(const int* __restrict__ src, const int* __restrict__ dst,
                   const float* __restrict__ w, int* __restrict__ cursor,
                   int2* __restrict__ tmp, int E, int NB) {
    __shared__ int h[NB_MAX];
    __shared__ int cur[NB_MAX];
    __shared__ int lstart[NB_MAX];
    __shared__ int gbase[NB_MAX];
    __shared__ int ws[4];
    __shared__ int2 pay[TILE];
    __shared__ unsigned short bk[TILE];

    for (int t = threadIdx.x; t < NB_MAX; t += 256) h[t] = 0;
    __syncthreads();

    const int base = blockIdx.x * TILE;
    int   myb[TILE / 256];
    int   myp[TILE / 256];
    float myw[TILE / 256];
#pragma unroll
    for (int i = 0; i < TILE / 256; ++i) {
        int e = base + i * 256 + threadIdx.x;
        if (e < E) {
            int d = dst[e];
            myb[i] = d >> 8;
            myp[i] = src[e] | ((d & 255) << 20);
            myw[i] = w[e];
            atomicAdd(&h[myb[i]], 1);
        } else {
            myb[i] = -1;
        }
    }
    __syncthreads();

    {   // exclusive scan of h[0..511] (thread t owns 2t, 2t+1)
        const int t = threadIdx.x, lane = t & 63, wid = t >> 6;
        int a = h[2 * t], b = h[2 * t + 1];
        int s = wave_incl_scan(a + b, lane);
        if (lane == 63) ws[wid] = s;
        __syncthreads();
        int add = 0;
        for (int i = 0; i < wid; ++i) add += ws[i];
        int excl = s + add - (a + b);
        lstart[2 * t] = excl;
        lstart[2 * t + 1] = excl + a;
        cur[2 * t] = excl;
        cur[2 * t + 1] = excl + a;
    }
    __syncthreads();

#pragma unroll
    for (int i = 0; i < TILE / 256; ++i) {
        if (myb[i] >= 0) {
            int p = atomicAdd(&cur[myb[i]], 1);
            pay[p] = make_int2(myp[i], __float_as_int(myw[i]));
            bk[p] = (unsigned short)myb[i];
        }
    }
    __syncthreads();

    for (int t = threadIdx.x; t < NB; t += 256) {
        int c = h[t];
        if (c) gbase[t] = atomicAdd(&cursor[t], c);
    }
    __syncthreads();

    const int total = min(TILE, E - base);
    for (int s2 = threadIdx.x; s2 < total; s2 += 256) {
        int b2 = bk[s2];
        tmp[gbase[b2] + s2 - lstart[b2]] = pay[s2];
    }
}

// ---------------------------------------------------------------------------
// p2: one block per bucket. LDS hist of 256 local dst -> scan -> rowStart +
// final dst-sorted edata (src, w fp32).
// ---------------------------------------------------------------------------
__global__ __launch_bounds__(256)
void p2_build(const int2* __restrict__ tmp, const int* __restrict__ bucketBase,
              int* __restrict__ rowStart, int2* __restrict__ edata,
              int N, int E, int NB) {
    const int b = blockIdx.x;
    const int s = bucketBase[b];
    const int e2 = (b + 1 < NB) ? bucketBase[b + 1] : E;
    __shared__ int h[256];
    __shared__ int cur[256];
    __shared__ int ws[4];
    h[threadIdx.x] = 0;
    __syncthreads();
    for (int j = s + threadIdx.x; j < e2; j += 256) {
        int dl = (tmp[j].x >> 20) & 255;
        atomicAdd(&h[dl], 1);
    }
    __syncthreads();
    const int t = threadIdx.x, lane = t & 63, wid = t >> 6;
    int v = h[t];
    int sc = wave_incl_scan(v, lane);
    if (lane == 63) ws[wid] = sc;
    __syncthreads();
    int add = 0;
    for (int i = 0; i < wid; ++i) add += ws[i];
    int excl = sc + add - v;
    const int node = b * 256 + t;
    if (node < N) rowStart[node] = s + excl;
    cur[t] = excl;
    __syncthreads();
    for (int j = s + threadIdx.x; j < e2; j += 256) {
        int2 v2 = tmp[j];
        int dl = (v2.x >> 20) & 255;
        int p = atomicAdd(&cur[dl], 1);
        edata[s + p] = make_int2(v2.x & 0x1FFFF, v2.y);
    }
}

// ---------------------------------------------------------------------------
// Gather, 16-edge-parallel, unconditional clamped loads (R8's proven shape:
// select on address, zero on weight; 4 edata + 4 row loads in flight).
// ---------------------------------------------------------------------------
__global__ __launch_bounds__(256)
void gather_kernel(const unsigned short* __restrict__ xB, const int* __restrict__ rowStart,
                   const int2* __restrict__ edata, unsigned short* __restrict__ aggB, int N) {
    const int node = blockIdx.x * 4 + (threadIdx.x >> 6);
    if (node >= N) return;
    const int lane = threadIdx.x & 63;
    const int grp  = lane >> 4;          // edge slot within quad
    const int f4   = (lane & 15) * 4;    // feature base (4 features/lane)
    const int s = rowStart[node];
    const int e = rowStart[node + 1];

    float a0 = 0.f, a1 = 0.f, a2 = 0.f, a3 = 0.f;
    for (int j = s; j < e; j += 16) {
        int   idx[4];
        int2  ed[4];
#pragma unroll
        for (int u = 0; u < 4; ++u) {
            int ii = j + u * 4 + grp;
            idx[u] = (ii < e) ? ii : s;
            ed[u] = edata[idx[u]];
        }
        ushort4 r[4];
#pragma unroll
        for (int u = 0; u < 4; ++u)
            r[u] = *(const ushort4*)(xB + (size_t)ed[u].x * 64 + f4);
#pragma unroll
        for (int u = 0; u < 4; ++u) {
            int ii = j + u * 4 + grp;
            float wv = (ii < e) ? __int_as_float(ed[u].y) : 0.0f;
            a0 += bf2f(r[u].x) * wv;  a1 += bf2f(r[u].y) * wv;
            a2 += bf2f(r[u].z) * wv;  a3 += bf2f(r[u].w) * wv;
        }
    }
    a0 += __shfl_xor(a0, 16, 64);  a1 += __shfl_xor(a1, 16, 64);
    a2 += __shfl_xor(a2, 16, 64);  a3 += __shfl_xor(a3, 16, 64);
    a0 += __shfl_xor(a0, 32, 64);  a1 += __shfl_xor(a1, 32, 64);
    a2 += __shfl_xor(a2, 32, 64);  a3 += __shfl_xor(a3, 32, 64);
    if (grp == 0) {
        ushort4 o = make_ushort4(f2bf(a0), f2bf(a1), f2bf(a2), f2bf(a3));
        *(ushort4*)(aggB + (size_t)node * 64 + f4) = o;
    }
}

// ---------------------------------------------------------------------------
// Transform, store variant: swapped MFMA operands -> transposed D -> ushort4
// stores.
// ---------------------------------------------------------------------------
__global__ __launch_bounds__(256)
void transform_store(const unsigned short* __restrict__ aggB,
                     const unsigned short* __restrict__ rootB,
                     const unsigned short* __restrict__ Bt,
                     const float* __restrict__ bias,
                     unsigned short* __restrict__ xoutB, int N) {
    const int wave = threadIdx.x >> 6;
    const int lane = threadIdx.x & 63;
    const int quad = lane >> 4;
    const int l16  = lane & 15;
    const int m0   = blockIdx.x * 128 + wave * 32;

    short8 bf[4][4];
#pragma unroll
    for (int t = 0; t < 4; ++t)
#pragma unroll
        for (int k = 0; k < 4; ++k)
            bf[t][k] = *(const short8*)(Bt + (t * 16 + l16) * 128 + k * 32 + quad * 8);

    f32x4 acc[2][4];
#pragma unroll
    for (int s = 0; s < 2; ++s)
#pragma unroll
        for (int t = 0; t < 4; ++t)
            acc[s][t] = (f32x4){0.f, 0.f, 0.f, 0.f};

#pragma unroll
    for (int s = 0; s < 2; ++s) {
        int row = m0 + s * 16 + l16;
        int rowc = row < N ? row : N - 1;
        const unsigned short* arow = aggB  + (size_t)rowc * 64;
        const unsigned short* xrow = rootB + (size_t)rowc * 64;
        short8 af[4];
        af[0] = *(const short8*)(arow + quad * 8);
        af[1] = *(const short8*)(arow + 32 + quad * 8);
        af[2] = *(const short8*)(xrow + quad * 8);
        af[3] = *(const short8*)(xrow + 32 + quad * 8);
#pragma unroll
        for (int t = 0; t < 4; ++t)
#pragma unroll
            for (int k = 0; k < 4; ++k)
                acc[s][t] = __builtin_amdgcn_mfma_f32_16x16x32_bf16(bf[t][k], af[k],
                                                                    acc[s][t], 0, 0, 0);
    }

#pragma unroll
    for (int s = 0; s < 2; ++s) {
        const int node = m0 + s * 16 + l16;
        if (node < N) {
#pragma unroll
            for (int t = 0; t < 4; ++t) {
                const float4 bb = *(const float4*)(bias + t * 16 + quad * 4);
                float v0 = acc[s][t][0] + bb.x;
                float v1 = acc[s][t][1] + bb.y;
                float v2 = acc[s][t][2] + bb.z;
                float v3 = acc[s][t][3] + bb.w;
                v0 = (v0 > 0.f) ? v0 : LEAKY_SLOPE * v0;
                v1 = (v1 > 0.f) ? v1 : LEAKY_SLOPE * v1;
                v2 = (v2 > 0.f) ? v2 : LEAKY_SLOPE * v2;
                v3 = (v3 > 0.f) ? v3 : LEAKY_SLOPE * v3;
                ushort4 o = make_ushort4(f2bf(v0), f2bf(v1), f2bf(v2), f2bf(v3));
                *(ushort4*)(xoutB + (size_t)node * 64 + t * 16 + quad * 4) = o;
            }
        }
    }
}

// ---------------------------------------------------------------------------
// Transform, pool variant: LDS-staged pooling (R9's win). batch is sorted; a
// 128-node block spans <=2 graphs in practice. Span overflow falls back to
// direct global atomics (correctness never depends on distribution).
// ---------------------------------------------------------------------------
__global__ __launch_bounds__(256)
void transform_pool(const unsigned short* __restrict__ aggB,
                    const unsigned short* __restrict__ rootB,
                    const unsigned short* __restrict__ Bt,
                    const float* __restrict__ bias,
                    const int* __restrict__ batch,
                    float* __restrict__ pooled, int N) {
    const int wave = threadIdx.x >> 6;
    const int lane = threadIdx.x & 63;
    const int quad = lane >> 4;
    const int l16  = lane & 15;
    const int m0   = blockIdx.x * 128 + wave * 32;

    __shared__ float lpool[POOL_SPAN * 64];
    const int gmin = batch[blockIdx.x * 128];
    for (int i = threadIdx.x; i < POOL_SPAN * 64; i += 256) lpool[i] = 0.f;

    short8 bf[4][4];
#pragma unroll
    for (int t = 0; t < 4; ++t)
#pragma unroll
        for (int k = 0; k < 4; ++k)
            bf[t][k] = *(const short8*)(Bt + (t * 16 + l16) * 128 + k * 32 + quad * 8);

    f32x4 acc[2][4];
#pragma unroll
    for (int s = 0; s < 2; ++s)
#pragma unroll
        for (int t = 0; t < 4; ++t)
            acc[s][t] = (f32x4){0.f, 0.f, 0.f, 0.f};

#pragma unroll
    for (int s = 0; s < 2; ++s) {
        int row = m0 + s * 16 + l16;
        int rowc = row < N ? row : N - 1;
        const unsigned short* arow = aggB  + (size_t)rowc * 64;
        const unsigned short* xrow = rootB + (size_t)rowc * 64;
        short8 af[4];
        af[0] = *(const short8*)(arow + quad * 8);
        af[1] = *(const short8*)(arow + 32 + quad * 8);
        af[2] = *(const short8*)(xrow + quad * 8);
        af[3] = *(const short8*)(xrow + 32 + quad * 8);
#pragma unroll
        for (int t = 0; t < 4; ++t)
#pragma unroll
            for (int k = 0; k < 4; ++k)
                acc[s][t] = __builtin_amdgcn_mfma_f32_16x16x32_bf16(af[k], bf[t][k],
                                                                    acc[s][t], 0, 0, 0);
    }

    __syncthreads();   // lpool zero-init complete

#pragma unroll
    for (int s = 0; s < 2; ++s) {
#pragma unroll
        for (int t = 0; t < 4; ++t) {
            const int col = t * 16 + l16;
            const float b = bias[col];
            const int rowbase = m0 + s * 16 + quad * 4;
            float v[4]; int g[4]; int nv = 0;
#pragma unroll
            for (int r = 0; r < 4; ++r) {
                int row = rowbase + r;
                if (row < N) {
                    float a = acc[s][t][r] + b;
                    a = (a > 0.0f) ? a : LEAKY_SLOPE * a;
                    v[nv] = a;
                    g[nv] = batch[row];
                    ++nv;
                }
            }
            if (nv == 4 && g[0] == g[3]) {
                int gl = g[0] - gmin;
                float sum = v[0] + v[1] + v[2] + v[3];
                if (gl < POOL_SPAN) atomicAdd(&lpool[gl * 64 + col], sum);
                else                atomicAdd(&pooled[g[0] * 64 + col], sum);
            } else {
                for (int r = 0; r < nv; ++r) {
                    int gl = g[r] - gmin;
                    if (gl < POOL_SPAN) atomicAdd(&lpool[gl * 64 + col], v[r]);
                    else                atomicAdd(&pooled[g[r] * 64 + col], v[r]);
                }
            }
        }
    }

    __syncthreads();
    for (int i = threadIdx.x; i < POOL_SPAN * 64; i += 256) {
        float v = lpool[i];
        if (v != 0.0f)
            atomicAdd(&pooled[(gmin + (i >> 6)) * 64 + (i & 63)], v);
    }
}

// ---------------------------------------------------------------------------
// Final: cnt via binary search on sorted batch; tiny GEMM epilogue.
// ---------------------------------------------------------------------------
__global__ __launch_bounds__(64)
void final_kernel(const float* __restrict__ pooled, const int* __restrict__ batch,
                  int N, const float* __restrict__ Wl, const float* __restrict__ bl,
                  float* __restrict__ out) {
    const int g = blockIdx.x;
    const int j = threadIdx.x;
    __shared__ float sp[64];
    __shared__ int scnt;
    if (j == 0) {
        int lo = 0, hi = N;
        while (lo < hi) { int mid = (lo + hi) >> 1; if (batch[mid] < g) lo = mid + 1; else hi = mid; }
        const int start = lo;
        hi = N;
        while (lo < hi) { int mid = (lo + hi) >> 1; if (batch[mid] < g + 1) lo = mid + 1; else hi = mid; }
        scnt = lo - start;
    }
    __syncthreads();
    const float c = fmaxf((float)scnt, 1.0f);
    sp[j] = pooled[g * 64 + j] / c;
    __syncthreads();
    if (j < 8) {
        float acc = bl[j];
#pragma unroll
        for (int k = 0; k < 64; ++k) acc += sp[k] * Wl[k * 8 + j];
        out[g * 8 + j] = acc;
    }
}

extern "C" void kernel_launch(void* const* d_in, const int* in_sizes, int n_in,
                              void* d_out, int out_size, void* d_ws, size_t ws_size,
                              hipStream_t stream) {
    const float* x      = (const float*)d_in[0];
    const int*   ei     = (const int*)  d_in[1];  // [2,E]: src then dst
    const float* w      = (const float*)d_in[2];
    const int*   batch  = (const int*)  d_in[3];
    const float* W1root = (const float*)d_in[4];
    const float* W1rel  = (const float*)d_in[5];
    const float* b1     = (const float*)d_in[6];
    const float* W2root = (const float*)d_in[7];
    const float* W2rel  = (const float*)d_in[8];
    const float* b2     = (const float*)d_in[9];
    const float* Wl     = (const float*)d_in[10];
    const float* bl     = (const float*)d_in[11];
    float* out = (float*)d_out;

    const int E = in_sizes[2];      // 1,250,000
    const int N = in_sizes[3];      // 100,000
    const int* src = ei;
    const int* dst = ei + E;
    const int NB = (N + 255) / 256; // 391 dst buckets

    // Workspace layout
    unsigned short* xB   = (unsigned short*)d_ws;          // [N*64] bf16
    unsigned short* aggB = xB   + (size_t)N * 64;          // [N*64]
    unsigned short* x1B  = aggB + (size_t)N * 64;          // [N*64]
    int2*  tmp      = (int2*)(x1B + (size_t)N * 64);       // [E]
    int2*  edata    = tmp + E;                             // [E]
    unsigned short* Bt1 = (unsigned short*)(edata + E);    // [64*128]
    unsigned short* Bt2 = Bt1 + 64 * 128;                  // [64*128]
    int*   rowStart = (int*)(Bt2 + 64 * 128);              // [N+1]
    int*   bucketCnt  = rowStart + (N + 1);                // [512]
    int*   bucketBase = bucketCnt + NB_MAX;                // [512]
    int*   cursor     = bucketBase + NB_MAX;               // [512]
    float* pooled   = (float*)(cursor + NB_MAX);           // [512*64]

    const int histBlocks = (E + TILE - 1) / TILE;          // 306
    const int xElems = N * 16;                              // float4 count
    const int xBlocks = (xElems + 255) / 256;               // 6250

    // ---- build + prep ----
    hipMemsetAsync(bucketCnt, 0, NB_MAX * sizeof(int), stream);
    mega_prep<<<histBlocks + xBlocks + 8, 256, 0, stream>>>(
        dst, bucketCnt, E, NB, histBlocks,
        x, xB, xElems, xBlocks,
        W1rel, W1root, W2rel, W2root, Bt1, Bt2);
    bscan_kernel<<<1, 512, 0, stream>>>(bucketCnt, bucketBase, cursor, rowStart,
                                        pooled, N, E, NB);
    p1b_partition<<<histBlocks, 256, 0, stream>>>(src, dst, w, cursor, tmp, E, NB);
    p2_build<<<NB, 256, 0, stream>>>(tmp, bucketBase, rowStart, edata, N, E, NB);

    const int tBlocks = (N + 127) / 128;
    // ---- Layer 1 ----
    gather_kernel<<<(N + 3) / 4, 256, 0, stream>>>(xB, rowStart, edata, aggB, N);
    transform_store<<<tBlocks, 256, 0, stream>>>(aggB, xB, Bt1, b1, x1B, N);
    // ---- Layer 2 ----
    gather_kernel<<<(N + 3) / 4, 256, 0, stream>>>(x1B, rowStart, edata, aggB, N);
    transform_pool<<<tBlocks, 256, 0, stream>>>(aggB, x1B, Bt2, b2, batch, pooled, N);
    // ---- Pool + classify ----
    final_kernel<<<NUM_GRAPHS, 64, 0, stream>>>(pooled, batch, N, Wl, bl, out);
}